// Round 7
// baseline (38.973 us; speedup 1.0000x reference)
//
#include <hip/hip_runtime.h>

// conv_transpose3d(x, identity weights, K=3, stride=1, pad=1) == gather:
//   out[b,z,y,w] = sum over (kz,ky,kx) of x[b, kz*9+ky*3+kx, z+1-kz, y+1-ky, w+1-kx]
// with out-of-range spatial taps contributing 0.
// Input  x:  (2, 27, 96, 96, 96) f32, ~191 MB (each element read exactly once)
// Output out:(2,  1, 96, 96, 96) f32, ~7 MB
// HBM-bound: floor ~198 MB; R4 (4-wide) 33.9us and R5 (8-wide) 34.1us both
// = ~5.8 TB/s -> BW-bound. This version: 4 outputs/thread (27 waves/CU) with
// non-temporal loads/stores via native clang vectors (input streamed once;
// skip cache allocation).

#define DIM 96
#define KK 3
#define NC 27

typedef float f32x4 __attribute__((ext_vector_type(4)));

__global__ __launch_bounds__(256) void fold_gather_nt_kernel(
    const float* __restrict__ x, float* __restrict__ out) {
  const int nWq = DIM / 4;  // 24 quads per row
  int tid = blockIdx.x * blockDim.x + threadIdx.x;

  int wq = tid % nWq;
  int t  = tid / nWq;
  int y  = t % DIM;
  t     /= DIM;
  int z  = t % DIM;
  int b  = t / DIM;
  int w0 = wq * 4;

  const size_t plane = (size_t)DIM * DIM * DIM;  // 884736
  const float* xb = x + (size_t)b * NC * plane;

  float a0 = 0.f, a1 = 0.f, a2 = 0.f, a3 = 0.f;

  const bool has_left  = (w0 > 0);
  const bool has_right = (w0 + 4 < DIM);

#pragma unroll
  for (int kz = 0; kz < KK; ++kz) {
    int zz = z + 1 - kz;
    if ((unsigned)zz >= (unsigned)DIM) continue;
#pragma unroll
    for (int ky = 0; ky < KK; ++ky) {
      int yy = y + 1 - ky;
      if ((unsigned)yy >= (unsigned)DIM) continue;

      int c0 = (kz * KK + ky) * KK;  // kx = 0,1,2 -> dx = +1, 0, -1
      const float* r_p = xb + (size_t)c0 * plane + (size_t)(zz * DIM + yy) * DIM;
      const float* r_0 = r_p + plane;
      const float* r_m = r_0 + plane;

      // Bases are multiples of 4 floats; w0 % 4 == 0 -> 16B-aligned vectors.
      f32x4 vp = __builtin_nontemporal_load((const f32x4*)(r_p + w0));
      f32x4 v0 = __builtin_nontemporal_load((const f32x4*)(r_0 + w0));
      f32x4 vm = __builtin_nontemporal_load((const f32x4*)(r_m + w0));
      float left  = has_left  ? __builtin_nontemporal_load(r_m + w0 - 1) : 0.f;
      float right = has_right ? __builtin_nontemporal_load(r_p + w0 + 4) : 0.f;

      // dx = 0:  out[w] += r_0[w]
      a0 += v0.x; a1 += v0.y; a2 += v0.z; a3 += v0.w;
      // dx = +1: out[w] += r_p[w+1]
      a0 += vp.y; a1 += vp.z; a2 += vp.w; a3 += right;
      // dx = -1: out[w] += r_m[w-1]
      a0 += left; a1 += vm.x; a2 += vm.y; a3 += vm.z;
    }
  }

  float* o = out + (size_t)((b * DIM + z) * DIM + y) * DIM + w0;
  f32x4 res; res.x = a0; res.y = a1; res.z = a2; res.w = a3;
  __builtin_nontemporal_store(res, (f32x4*)o);
}

extern "C" void kernel_launch(void* const* d_in, const int* in_sizes, int n_in,
                              void* d_out, int out_size, void* d_ws, size_t ws_size,
                              hipStream_t stream) {
  (void)in_sizes; (void)n_in; (void)d_ws; (void)ws_size; (void)out_size;
  const float* x = (const float*)d_in[0];
  float* out = (float*)d_out;

  // total threads: B * D * D * (D/4) = 2 * 96 * 96 * 24 = 442368 (multiple of 256)
  const int total_threads = 2 * DIM * DIM * (DIM / 4);
  const int block = 256;
  const int grid = total_threads / block;  // 1728
  fold_gather_nt_kernel<<<grid, block, 0, stream>>>(x, out);
}

// Round 8
// 33.805 us; speedup vs baseline: 1.1529x; 1.1529x over previous
//
#include <hip/hip_runtime.h>

// conv_transpose3d(x, identity weights, K=3, stride=1, pad=1) == gather:
//   out[b,z,y,w] = sum over (kz,ky,kx) of x[b, kz*9+ky*3+kx, z+1-kz, y+1-ky, w+1-kx]
// with out-of-range spatial taps contributing 0.
// Input  x:  (2, 27, 96, 96, 96) f32, ~191 MB (read exactly once)
// Output out:(2,  1, 96, 96, 96) f32, ~7 MB
// HBM-bound: floor ~198 MB / ~6 TB/s ~= 32-34 us.
// Session evidence: 4-wide cached = 33.9us (this kernel), 8-wide = 34.1us
// (issue-side neutral -> BW-bound), nontemporal = 39.0us (NT bypasses L2
// allocation; boundary scalars re-fetch lines from HBM -> regression).
// This is the session-best R4 kernel: 4 outputs/thread, cached float4 loads,
// 27 waves/CU.

#define DIM 96
#define KK 3
#define NC 27

__global__ __launch_bounds__(256) void fold_gather_kernel(
    const float* __restrict__ x, float* __restrict__ out) {
  const int nWq = DIM / 4;  // 24 quads per row
  int tid = blockIdx.x * blockDim.x + threadIdx.x;

  int wq = tid % nWq;
  int t  = tid / nWq;
  int y  = t % DIM;
  t     /= DIM;
  int z  = t % DIM;
  int b  = t / DIM;
  int w0 = wq * 4;

  const size_t plane = (size_t)DIM * DIM * DIM;  // 884736 (multiple of 4)
  const float* xb = x + (size_t)b * NC * plane;

  float a0 = 0.f, a1 = 0.f, a2 = 0.f, a3 = 0.f;

  const bool has_left  = (w0 > 0);
  const bool has_right = (w0 + 4 < DIM);

#pragma unroll
  for (int kz = 0; kz < KK; ++kz) {
    int zz = z + 1 - kz;
    if ((unsigned)zz >= (unsigned)DIM) continue;
#pragma unroll
    for (int ky = 0; ky < KK; ++ky) {
      int yy = y + 1 - ky;
      if ((unsigned)yy >= (unsigned)DIM) continue;

      int c0 = (kz * KK + ky) * KK;  // kx = 0,1,2 -> dx = +1, 0, -1
      const float* r_p = xb + (size_t)c0 * plane + (size_t)(zz * DIM + yy) * DIM;
      const float* r_0 = r_p + plane;
      const float* r_m = r_0 + plane;

      // All bases are multiples of 4 floats (96 | row stride), w0 % 4 == 0:
      // 16B-aligned vector loads, consecutive lanes -> contiguous 16B chunks.
      float4 vp = *(const float4*)(r_p + w0);  // dx=+1 channel
      float4 v0 = *(const float4*)(r_0 + w0);  // dx= 0 channel
      float4 vm = *(const float4*)(r_m + w0);  // dx=-1 channel
      float left  = has_left  ? r_m[w0 - 1] : 0.f;  // out w0   needs r_m[w0-1]
      float right = has_right ? r_p[w0 + 4] : 0.f;  // out w0+3 needs r_p[w0+4]

      // dx = 0:  out[w] += r_0[w]
      a0 += v0.x; a1 += v0.y; a2 += v0.z; a3 += v0.w;
      // dx = +1: out[w] += r_p[w+1]
      a0 += vp.y; a1 += vp.z; a2 += vp.w; a3 += right;
      // dx = -1: out[w] += r_m[w-1]
      a0 += left; a1 += vm.x; a2 += vm.y; a3 += vm.z;
    }
  }

  float* o = out + (size_t)((b * DIM + z) * DIM + y) * DIM + w0;
  *(float4*)o = make_float4(a0, a1, a2, a3);
}

extern "C" void kernel_launch(void* const* d_in, const int* in_sizes, int n_in,
                              void* d_out, int out_size, void* d_ws, size_t ws_size,
                              hipStream_t stream) {
  (void)in_sizes; (void)n_in; (void)d_ws; (void)ws_size; (void)out_size;
  const float* x = (const float*)d_in[0];
  float* out = (float*)d_out;

  // total threads: B * D * D * (D/4) = 2 * 96 * 96 * 24 = 442368 (multiple of 256)
  const int total_threads = 2 * DIM * DIM * (DIM / 4);
  const int block = 256;
  const int grid = total_threads / block;  // 1728
  fold_gather_kernel<<<grid, block, 0, stream>>>(x, out);
}